// Round 12
// baseline (148.104 us; speedup 1.0000x reference)
//
#include <hip/hip_runtime.h>
#include <math.h>

constexpr int LEN = 4096;
constexpr int NTHREADS = 512;   // 8 elems/thread; 512 radix-8 butterflies/stage
constexpr int PELEM = LEN / NTHREADS;   // 8
constexpr float INVN = 1.0f / 4096.0f;
constexpr float RHALF = 0.70710678118654752440f;   // sqrt(1/2)
constexpr float C8 = 0.92387953251128675613f;      // cos(pi/8)
constexpr float S8 = -0.38268343236508977173f;     // -sin(pi/8)  (W^256 = C8 + i*S8)

typedef __attribute__((ext_vector_type(8))) short bf16x8;
typedef __attribute__((ext_vector_type(4))) float f32x4;

// (i>>5) padding — empirically best (8.4e6 conflicts vs 10.75e6 (>>6), 19e6 (>>4))
#define APHYS(I) ((I) + ((I) >> 5))
#define TPHYS(I) ((I) + ((I) >> 5))

__device__ __forceinline__ unsigned short f2bf(float f) {
    unsigned u = __float_as_uint(f);
    unsigned r = (u + 0x7fffu + ((u >> 16) & 1u)) >> 16;
    return (unsigned short)r;
}

// reverse 4 base-8 digits of a 12-bit index
__device__ __forceinline__ int digitrev8(int j) {
    return ((j & 7) << 9) | (((j >> 3) & 7) << 6) | (((j >> 6) & 7) << 3) | (j >> 9);
}

__device__ __forceinline__ void cmul(float ar, float ai, float br, float bi,
                                     float& cr, float& ci) {
    cr = ar * br - ai * bi;
    ci = ar * bi + ai * br;
}

// w1 = W^k1 (conj if CONJ), k1 in [0,512), from a 256-entry table:
// k1 >= 256: W^k1 = W^256 * W^(k1-256), W^256 = C8 + i*S8. (round-8-style fold)
template <bool CONJ>
__device__ __forceinline__ void loadw1(const float* __restrict__ twr,
                                       const float* __restrict__ twi, int k1,
                                       float& w1r, float& w1i) {
    int m = k1 & 255;
    float c = twr[TPHYS(m)], s = twi[TPHYS(m)];
    bool hi = (k1 & 256) != 0;
    float cr = c * C8 - s * S8;
    float ci = c * S8 + s * C8;
    c = hi ? cr : c;
    s = hi ? ci : s;
    w1r = c;
    w1i = CONJ ? -s : s;
}

// Radix-8 DIF (Gentleman-Sande): natural-order input, base-8 digit-reversed
// output. 4 stages; stage s: E = 8^(3-s), k1 = j*8^s < 512.
__device__ void dif_fft8(float* __restrict__ ar, float* __restrict__ ai,
                         const float* __restrict__ twr, const float* __restrict__ twi,
                         int tid) {
#pragma unroll
    for (int s = 0; s < 4; ++s) {
        __syncthreads();
        const int eshift = 3 * (3 - s);
        const int E = 1 << eshift;
        int j = tid & (E - 1);
        int g = tid >> eshift;
        int base = (g << (eshift + 3)) + j;

        float xr[8], xi[8];
#pragma unroll
        for (int m = 0; m < 8; ++m) {
            int idx = APHYS(base + (m << eshift));
            xr[m] = ar[idx]; xi[m] = ai[idx];
        }
        // ---- forward DFT8 (radix-2^3), omega = e^{-2pi i/8} ----
        float b0r = xr[0] + xr[4], b0i = xi[0] + xi[4];
        float b1r = xr[1] + xr[5], b1i = xi[1] + xi[5];
        float b2r = xr[2] + xr[6], b2i = xi[2] + xi[6];
        float b3r = xr[3] + xr[7], b3i = xi[3] + xi[7];
        float c0r = xr[0] - xr[4], c0i = xi[0] - xi[4];
        float c1r = xr[1] - xr[5], c1i = xi[1] - xi[5];
        float c2r = xr[2] - xr[6], c2i = xi[2] - xi[6];
        float c3r = xr[3] - xr[7], c3i = xi[3] - xi[7];
        float d1r = RHALF * (c1r + c1i), d1i = RHALF * (c1i - c1r);
        float d2r = c2i,               d2i = -c2r;
        float d3r = -RHALF * (c3r - c3i), d3i = -RHALF * (c3r + c3i);
        float t0r = b0r + b2r, t0i = b0i + b2i;
        float t1r = b0r - b2r, t1i = b0i - b2i;
        float t2r = b1r + b3r, t2i = b1i + b3i;
        float t3r = b1r - b3r, t3i = b1i - b3i;
        xr[0] = t0r + t2r; xi[0] = t0i + t2i;
        xr[2] = t1r + t3i; xi[2] = t1i - t3r;
        xr[4] = t0r - t2r; xi[4] = t0i - t2i;
        xr[6] = t1r - t3i; xi[6] = t1i + t3r;
        t0r = c0r + d2r; t0i = c0i + d2i;
        t1r = c0r - d2r; t1i = c0i - d2i;
        t2r = d1r + d3r; t2i = d1i + d3i;
        t3r = d1r - d3r; t3i = d1i - d3i;
        xr[1] = t0r + t2r; xi[1] = t0i + t2i;
        xr[3] = t1r + t3i; xi[3] = t1i - t3r;
        xr[5] = t0r - t2r; xi[5] = t0i - t2i;
        xr[7] = t1r - t3i; xi[7] = t1i + t3r;

        if (s < 3) {   // last stage (E=1): j=0 -> unit twiddles
            int k1 = j << (3 * s);
            float w1r, w1i;
            loadw1<false>(twr, twi, k1, w1r, w1i);
            float w2r, w2i, w3r, w3i, w4r, w4i, w5r, w5i, w6r, w6i, w7r, w7i;
            cmul(w1r, w1i, w1r, w1i, w2r, w2i);
            cmul(w2r, w2i, w1r, w1i, w3r, w3i);
            cmul(w2r, w2i, w2r, w2i, w4r, w4i);
            cmul(w4r, w4i, w1r, w1i, w5r, w5i);
            cmul(w4r, w4i, w2r, w2i, w6r, w6i);
            cmul(w4r, w4i, w3r, w3i, w7r, w7i);
            float orr, oii;
            cmul(xr[1], xi[1], w1r, w1i, orr, oii); xr[1] = orr; xi[1] = oii;
            cmul(xr[2], xi[2], w2r, w2i, orr, oii); xr[2] = orr; xi[2] = oii;
            cmul(xr[3], xi[3], w3r, w3i, orr, oii); xr[3] = orr; xi[3] = oii;
            cmul(xr[4], xi[4], w4r, w4i, orr, oii); xr[4] = orr; xi[4] = oii;
            cmul(xr[5], xi[5], w5r, w5i, orr, oii); xr[5] = orr; xi[5] = oii;
            cmul(xr[6], xi[6], w6r, w6i, orr, oii); xr[6] = orr; xi[6] = oii;
            cmul(xr[7], xi[7], w7r, w7i, orr, oii); xr[7] = orr; xi[7] = oii;
        }
#pragma unroll
        for (int m = 0; m < 8; ++m) {
            int idx = APHYS(base + (m << eshift));
            ar[idx] = xr[m]; ai[idx] = xi[m];
        }
    }
    __syncthreads();
}

// Radix-8 DIT inverse (conjugate twiddles pre-applied): digit-reversed input,
// natural output, UNNORMALIZED. Stage s: E = 8^s, k1 = j*8^(3-s) < 512.
__device__ void dit_ifft8(float* __restrict__ ar, float* __restrict__ ai,
                          const float* __restrict__ twr, const float* __restrict__ twi,
                          int tid) {
#pragma unroll
    for (int s = 0; s < 4; ++s) {
        __syncthreads();
        const int eshift = 3 * s;
        const int E = 1 << eshift;
        int j = tid & (E - 1);
        int g = tid >> eshift;
        int base = (g << (eshift + 3)) + j;

        float xr[8], xi[8];
#pragma unroll
        for (int m = 0; m < 8; ++m) {
            int idx = APHYS(base + (m << eshift));
            xr[m] = ar[idx]; xi[m] = ai[idx];
        }
        if (s > 0) {   // first stage (E=1): unit twiddles
            int k1 = j << (3 * (3 - s));
            float w1r, w1i;
            loadw1<true>(twr, twi, k1, w1r, w1i);
            float w2r, w2i, w3r, w3i, w4r, w4i, w5r, w5i, w6r, w6i, w7r, w7i;
            cmul(w1r, w1i, w1r, w1i, w2r, w2i);
            cmul(w2r, w2i, w1r, w1i, w3r, w3i);
            cmul(w2r, w2i, w2r, w2i, w4r, w4i);
            cmul(w4r, w4i, w1r, w1i, w5r, w5i);
            cmul(w4r, w4i, w2r, w2i, w6r, w6i);
            cmul(w4r, w4i, w3r, w3i, w7r, w7i);
            float orr, oii;
            cmul(xr[1], xi[1], w1r, w1i, orr, oii); xr[1] = orr; xi[1] = oii;
            cmul(xr[2], xi[2], w2r, w2i, orr, oii); xr[2] = orr; xi[2] = oii;
            cmul(xr[3], xi[3], w3r, w3i, orr, oii); xr[3] = orr; xi[3] = oii;
            cmul(xr[4], xi[4], w4r, w4i, orr, oii); xr[4] = orr; xi[4] = oii;
            cmul(xr[5], xi[5], w5r, w5i, orr, oii); xr[5] = orr; xi[5] = oii;
            cmul(xr[6], xi[6], w6r, w6i, orr, oii); xr[6] = orr; xi[6] = oii;
            cmul(xr[7], xi[7], w7r, w7i, orr, oii); xr[7] = orr; xi[7] = oii;
        }
        // ---- inverse DFT8, omega = e^{+2pi i/8} ----
        float b0r = xr[0] + xr[4], b0i = xi[0] + xi[4];
        float b1r = xr[1] + xr[5], b1i = xi[1] + xi[5];
        float b2r = xr[2] + xr[6], b2i = xi[2] + xi[6];
        float b3r = xr[3] + xr[7], b3i = xi[3] + xi[7];
        float c0r = xr[0] - xr[4], c0i = xi[0] - xi[4];
        float c1r = xr[1] - xr[5], c1i = xi[1] - xi[5];
        float c2r = xr[2] - xr[6], c2i = xi[2] - xi[6];
        float c3r = xr[3] - xr[7], c3i = xi[3] - xi[7];
        float d1r = RHALF * (c1r - c1i), d1i = RHALF * (c1r + c1i);
        float d2r = -c2i,              d2i = c2r;
        float d3r = -RHALF * (c3r + c3i), d3i = RHALF * (c3r - c3i);
        float t0r = b0r + b2r, t0i = b0i + b2i;
        float t1r = b0r - b2r, t1i = b0i - b2i;
        float t2r = b1r + b3r, t2i = b1i + b3i;
        float t3r = b1r - b3r, t3i = b1i - b3i;
        xr[0] = t0r + t2r; xi[0] = t0i + t2i;
        xr[2] = t1r - t3i; xi[2] = t1i + t3r;
        xr[4] = t0r - t2r; xi[4] = t0i - t2i;
        xr[6] = t1r + t3i; xi[6] = t1i - t3r;
        t0r = c0r + d2r; t0i = c0i + d2i;
        t1r = c0r - d2r; t1i = c0i - d2i;
        t2r = d1r + d3r; t2i = d1i + d3i;
        t3r = d1r - d3r; t3i = d1i - d3i;
        xr[1] = t0r + t2r; xi[1] = t0i + t2i;
        xr[3] = t1r - t3i; xi[3] = t1i + t3r;
        xr[5] = t0r - t2r; xi[5] = t0i - t2i;
        xr[7] = t1r + t3i; xi[7] = t1i - t3r;

#pragma unroll
        for (int m = 0; m < 8; ++m) {
            int idx = APHYS(base + (m << eshift));
            ar[idx] = xr[m]; ai[idx] = xi[m];
        }
    }
    __syncthreads();
}

// One WG (512 thr) per (batch, channel-pair). 1 fwd + 3 masked inverse
// radix-8 LDS FFTs; band3 = x(global, exact) - acc; conv+BN+GELU from packed
// bf16 z (round-8/9-validated data path). LDS 52.3 KB + VGPR<=85 -> 3 blk/CU.
__global__ __launch_bounds__(512) void k_bands(
    const float* __restrict__ x,
    const float* __restrict__ cw0, const float* __restrict__ cw1,
    const float* __restrict__ cw2, const float* __restrict__ cw3,
    const float* __restrict__ bng, const float* __restrict__ bnb,
    const float* __restrict__ bnm, const float* __restrict__ bnv,
    const float* __restrict__ sw, const float* __restrict__ alp,
    unsigned int* __restrict__ Fu) {
    __shared__ float wr[4224], wi[4224];   // APHYS(4095)=4222
    __shared__ float twr[264], twi[264];   // TPHYS(255)=262
    __shared__ unsigned zpk[LEN];          // bf16(c0) | bf16(c1)<<16

    const int tid = threadIdx.x;
    const int pair = blockIdx.x;   // 0..63
    const int b = blockIdx.y;
    const int c0 = 2 * pair, c1 = c0 + 1;

    const float* xp0 = x + ((size_t)b * 128 + c0) * LEN;
    const float* xp1 = xp0 + LEN;
#pragma unroll
    for (int p = 0; p < PELEM; ++p) {
        int l = tid + NTHREADS * p;
        float a0 = xp0[l], a1 = xp1[l];
        zpk[l] = (unsigned)f2bf(a0) | ((unsigned)f2bf(a1) << 16);
        wr[APHYS(l)] = a0; wi[APHYS(l)] = a1;
    }
    if (tid < 256) {
        int jj = tid;
        float ang = -(float)(2.0 * M_PI / 4096.0) * (float)jj;
        float sv, cv;
        sincosf(ang, &sv, &cv);
        twr[TPHYS(jj)] = cv; twi[TPHYS(jj)] = sv;
    }
    dif_fft8(wr, wi, twr, twi, tid);   // stage-top sync covers writes above

    float Zre[PELEM], Zim[PELEM];
#pragma unroll
    for (int p = 0; p < PELEM; ++p) {
        int l = tid + NTHREADS * p;
        Zre[p] = wr[APHYS(l)]; Zim[p] = wi[APHYS(l)];
    }

    float s0w = sw[0], s1w = sw[1], s2w = sw[2], s3w = sw[3];
    float mx = fmaxf(fmaxf(s0w, s1w), fmaxf(s2w, s3w));
    float e0 = expf(s0w - mx), e1 = expf(s1w - mx), e2 = expf(s2w - mx), e3 = expf(s3w - mx);
    float esum = e0 + e1 + e2 + e3;
    float nwv[4] = {e0 / esum, e1 / esum, e2 / esum, e3 / esum};
    float alpha_s = 1.0f / (1.0f + expf(-alp[0]));
    float oma = 1.0f - alpha_s;

    const float* cwp[4] = {cw0, cw1, cw2, cw3};
    const int kk4[4] = {3, 5, 7, 11};

    float accr[PELEM], acci[PELEM];
#pragma unroll
    for (int p = 0; p < PELEM; ++p) { accr[p] = 0.f; acci[p] = 0.f; }

    unsigned int* dst = Fu + (size_t)b * (512 * LEN / 2);
    const int n = tid & 15;

#pragma unroll
    for (int band = 0; band < 4; ++band) {
        if (band < 3) {
            const int fs = band * 512, fe = fs + 512;
#pragma unroll
            for (int p = 0; p < PELEM; ++p) {
                int j = tid + NTHREADS * p;
                int f = digitrev8(j);
                int fi = (f <= 2048) ? f : (4096 - f);
                bool keep = (fi >= fs) && (fi < fe);
                wr[APHYS(j)] = keep ? Zre[p] : 0.0f;
                wi[APHYS(j)] = keep ? Zim[p] : 0.0f;
            }
            dit_ifft8(wr, wi, twr, twi, tid);
        }

        const float* cw = cwp[band];
        const int kk = kk4[band];
        const int kh = kk >> 1;
        float w0c[11], w1c[11];
        for (int q = 0; q < kk; ++q) {
            w0c[q] = cw[c0 * kk + q];
            w1c[q] = cw[c1 * kk + q];
        }
        float A0 = rsqrtf(bnv[band * 128 + c0] + 1e-5f) * bng[band * 128 + c0];
        float B0 = bnb[band * 128 + c0] - bnm[band * 128 + c0] * A0;
        float A1 = rsqrtf(bnv[band * 128 + c1] + 1e-5f) * bng[band * 128 + c1];
        float B1 = bnb[band * 128 + c1] - bnm[band * 128 + c1] * A1;
        float nww = nwv[band];
#pragma unroll
        for (int p = 0; p < PELEM; ++p) {
            int l = tid + NTHREADS * p;
            float bvr, bvi;
            if (band < 3) {
                bvr = wr[APHYS(l)] * INVN;   // own-slot read: no hazard
                bvi = wi[APHYS(l)] * INVN;
                accr[p] += bvr;
                acci[p] += bvi;
            } else {
                bvr = xp0[l] - accr[p];      // exact x from global (L2-hot)
                bvi = xp1[l] - acci[p];
            }
            float s0 = 0.f, s1 = 0.f;
#pragma unroll
            for (int q = 0; q < 11; ++q) {
                if (q < kk) {
                    int idx = l + q - kh;
                    bool ok = (idx >= 0) && (idx < LEN);
                    int ic = ok ? idx : 0;
                    unsigned uv = zpk[ic];
                    float v0 = ok ? __uint_as_float(uv << 16) : 0.0f;
                    float v1 = ok ? __uint_as_float(uv & 0xffff0000u) : 0.0f;
                    s0 += v0 * w0c[q];
                    s1 += v1 * w1c[q];
                }
            }
            float y0 = s0 * A0 + B0;
            y0 = 0.5f * y0 * (1.0f + erff(y0 * RHALF)) * nww;
            float y1 = s1 * A1 + B1;
            y1 = 0.5f * y1 * (1.0f + erff(y1 * RHALF)) * nww;
            float f0 = alpha_s * y0 + oma * bvr;
            float f1 = alpha_s * y1 + oma * bvi;
            int lb = (tid >> 4) + 32 * p;   // l>>4 with l = tid + 512p
            unsigned int val = (unsigned int)f2bf(f0) | ((unsigned int)f2bf(f1) << 16);
            // k-permutation: g = pair, j = 2*band + (c&1) -> u32 slot = band
            dst[((lb * 64 + pair) * 16 + n) * 4 + band] = val;
        }
    }
}

// W (fp32 [256][512]) -> bf16 in MFMA A-fragment order, matching k-permutation:
// k = band*128 + 2*pair + lo  ->  (g = pair, j = 2*band + lo)
__global__ void k_prep(const float* __restrict__ pw, unsigned short* __restrict__ Wq) {
    int idx = blockIdx.x * 256 + threadIdx.x;   // 131072
    int o = idx >> 9, c = idx & 511;
    int band = c >> 7, pair = (c & 127) >> 1, lo = c & 1;
    int dstidx = (((o >> 4) * 64 + pair) * 16 + (o & 15)) * 8 + 2 * band + lo;
    Wq[dstidx] = f2bf(pw[idx]);
}

// LDS-free MFMA GEMM: out[b,o,l] = bias[o] + sum_k W[o,k]*F[b,k,l]
__global__ __launch_bounds__(256) void k_gemm(
    const unsigned short* __restrict__ Wq, const unsigned short* __restrict__ Fq,
    const float* __restrict__ pb, float* __restrict__ out) {
    const int tid = threadIdx.x;
    const int wave = tid >> 6, lane = tid & 63;
    const int h = lane >> 4, n16 = lane & 15;
    const int lt = blockIdx.x, b = blockIdx.y;
    const unsigned short* Fb = Fq + (size_t)b * 2097152;

    f32x4 acc[4][4];
#pragma unroll
    for (int mi = 0; mi < 4; ++mi)
#pragma unroll
        for (int ni = 0; ni < 4; ++ni) acc[mi][ni] = (f32x4){0.f, 0.f, 0.f, 0.f};

#pragma unroll
    for (int ks = 0; ks < 16; ++ks) {
        bf16x8 af[4], bfr[4];
#pragma unroll
        for (int mi = 0; mi < 4; ++mi) {
            int mb = wave * 4 + mi;
            af[mi] = *(const bf16x8*)(Wq + ((((mb * 64) + 4 * ks + h) * 16 + n16) << 3));
        }
#pragma unroll
        for (int ni = 0; ni < 4; ++ni) {
            int lb = lt * 4 + ni;
            bfr[ni] = *(const bf16x8*)(Fb + ((((lb * 64) + 4 * ks + h) * 16 + n16) << 3));
        }
#pragma unroll
        for (int mi = 0; mi < 4; ++mi)
#pragma unroll
            for (int ni = 0; ni < 4; ++ni)
                acc[mi][ni] = __builtin_amdgcn_mfma_f32_16x16x32_bf16(
                    af[mi], bfr[ni], acc[mi][ni], 0, 0, 0);
    }

#pragma unroll
    for (int mi = 0; mi < 4; ++mi) {
#pragma unroll
        for (int r = 0; r < 4; ++r) {
            int o = wave * 64 + mi * 16 + h * 4 + r;
            float bias = pb[o];
#pragma unroll
            for (int ni = 0; ni < 4; ++ni) {
                int l = lt * 64 + ni * 16 + n16;
                out[((size_t)(b * 256 + o)) * LEN + l] = acc[mi][ni][r] + bias;
            }
        }
    }
}

extern "C" void kernel_launch(void* const* d_in, const int* in_sizes, int n_in,
                              void* d_out, int out_size, void* d_ws, size_t ws_size,
                              hipStream_t stream) {
    const float* x   = (const float*)d_in[0];
    const float* cw0 = (const float*)d_in[1];
    const float* cw1 = (const float*)d_in[2];
    const float* cw2 = (const float*)d_in[3];
    const float* cw3 = (const float*)d_in[4];
    const float* bng = (const float*)d_in[5];
    const float* bnb = (const float*)d_in[6];
    const float* bnm = (const float*)d_in[7];
    const float* bnv = (const float*)d_in[8];
    const float* sw  = (const float*)d_in[9];
    const float* alp = (const float*)d_in[10];
    const float* pw  = (const float*)d_in[11];
    const float* pb  = (const float*)d_in[12];
    float* out = (float*)d_out;

    unsigned short* Wq = (unsigned short*)d_ws;                       // 256 KB
    unsigned int* Fu = (unsigned int*)((char*)d_ws + 262144);         // 4 MB/batch

    k_prep<<<512, 256, 0, stream>>>(pw, Wq);

    const size_t perB = (size_t)512 * LEN * 2;   // 4 MiB bf16 per batch
    int chunk = (int)((ws_size > 262144 ? ws_size - 262144 : 0) / perB);
    if (chunk < 1) chunk = 1;
    if (chunk > 16) chunk = 16;

    for (int b0 = 0; b0 < 16; b0 += chunk) {
        int nb = 16 - b0 < chunk ? 16 - b0 : chunk;
        dim3 g1(64, nb);
        k_bands<<<g1, NTHREADS, 0, stream>>>(
            x + (size_t)b0 * 128 * LEN, cw0, cw1, cw2, cw3,
            bng, bnb, bnm, bnv, sw, alp, Fu);
        dim3 g2(64, nb);
        k_gemm<<<g2, 256, 0, stream>>>(
            Wq, (const unsigned short*)Fu, pb, out + (size_t)b0 * 256 * LEN);
    }
}

// Round 13
// 135.878 us; speedup vs baseline: 1.0900x; 1.0900x over previous
//
#include <hip/hip_runtime.h>
#include <math.h>

constexpr int LEN = 4096;
constexpr int NTHREADS = 512;   // 8 elems/thread; 512 radix-8 butterflies/stage
constexpr int PELEM = LEN / NTHREADS;   // 8
constexpr float INVN = 1.0f / 4096.0f;
constexpr float RHALF = 0.70710678118654752440f;   // sqrt(1/2)

typedef __attribute__((ext_vector_type(8))) short bf16x8;
typedef __attribute__((ext_vector_type(4))) float f32x4;

// (i>>5) padding — empirically best (8.4e6 conflicts vs 10.75e6 (>>6), 19e6 (>>4))
#define APHYS(I) ((I) + ((I) >> 5))
#define TPHYS(I) ((I) + ((I) >> 5))
#define ZOFF 8

__device__ __forceinline__ unsigned short f2bf(float f) {
    unsigned u = __float_as_uint(f);
    unsigned r = (u + 0x7fffu + ((u >> 16) & 1u)) >> 16;
    return (unsigned short)r;
}

// reverse 3 base-8 digits of a 9-bit index
__device__ __forceinline__ int drev3(int t) {
    return ((t & 7) << 6) | (((t >> 3) & 7) << 3) | (t >> 6);
}

__device__ __forceinline__ void cmul(float ar, float ai, float br, float bi,
                                     float& cr, float& ci) {
    cr = ar * br - ai * bi;
    ci = ar * bi + ai * br;
}

// ---- DFT8 cores (r10-validated, register arrays) ----
__device__ __forceinline__ void dft8_fwd(float (&xr)[8], float (&xi)[8]) {
    float b0r = xr[0] + xr[4], b0i = xi[0] + xi[4];
    float b1r = xr[1] + xr[5], b1i = xi[1] + xi[5];
    float b2r = xr[2] + xr[6], b2i = xi[2] + xi[6];
    float b3r = xr[3] + xr[7], b3i = xi[3] + xi[7];
    float c0r = xr[0] - xr[4], c0i = xi[0] - xi[4];
    float c1r = xr[1] - xr[5], c1i = xi[1] - xi[5];
    float c2r = xr[2] - xr[6], c2i = xi[2] - xi[6];
    float c3r = xr[3] - xr[7], c3i = xi[3] - xi[7];
    float d1r = RHALF * (c1r + c1i), d1i = RHALF * (c1i - c1r);
    float d2r = c2i,               d2i = -c2r;
    float d3r = -RHALF * (c3r - c3i), d3i = -RHALF * (c3r + c3i);
    float t0r = b0r + b2r, t0i = b0i + b2i;
    float t1r = b0r - b2r, t1i = b0i - b2i;
    float t2r = b1r + b3r, t2i = b1i + b3i;
    float t3r = b1r - b3r, t3i = b1i - b3i;
    xr[0] = t0r + t2r; xi[0] = t0i + t2i;
    xr[2] = t1r + t3i; xi[2] = t1i - t3r;
    xr[4] = t0r - t2r; xi[4] = t0i - t2i;
    xr[6] = t1r - t3i; xi[6] = t1i + t3r;
    t0r = c0r + d2r; t0i = c0i + d2i;
    t1r = c0r - d2r; t1i = c0i - d2i;
    t2r = d1r + d3r; t2i = d1i + d3i;
    t3r = d1r - d3r; t3i = d1i - d3i;
    xr[1] = t0r + t2r; xi[1] = t0i + t2i;
    xr[3] = t1r + t3i; xi[3] = t1i - t3r;
    xr[5] = t0r - t2r; xi[5] = t0i - t2i;
    xr[7] = t1r - t3i; xi[7] = t1i + t3r;
}

__device__ __forceinline__ void dft8_inv(float (&xr)[8], float (&xi)[8]) {
    float b0r = xr[0] + xr[4], b0i = xi[0] + xi[4];
    float b1r = xr[1] + xr[5], b1i = xi[1] + xi[5];
    float b2r = xr[2] + xr[6], b2i = xi[2] + xi[6];
    float b3r = xr[3] + xr[7], b3i = xi[3] + xi[7];
    float c0r = xr[0] - xr[4], c0i = xi[0] - xi[4];
    float c1r = xr[1] - xr[5], c1i = xi[1] - xi[5];
    float c2r = xr[2] - xr[6], c2i = xi[2] - xi[6];
    float c3r = xr[3] - xr[7], c3i = xi[3] - xi[7];
    float d1r = RHALF * (c1r - c1i), d1i = RHALF * (c1r + c1i);
    float d2r = -c2i,              d2i = c2r;
    float d3r = -RHALF * (c3r + c3i), d3i = RHALF * (c3r - c3i);
    float t0r = b0r + b2r, t0i = b0i + b2i;
    float t1r = b0r - b2r, t1i = b0i - b2i;
    float t2r = b1r + b3r, t2i = b1i + b3i;
    float t3r = b1r - b3r, t3i = b1i - b3i;
    xr[0] = t0r + t2r; xi[0] = t0i + t2i;
    xr[2] = t1r - t3i; xi[2] = t1i + t3r;
    xr[4] = t0r - t2r; xi[4] = t0i - t2i;
    xr[6] = t1r + t3i; xi[6] = t1i - t3r;
    t0r = c0r + d2r; t0i = c0i + d2i;
    t1r = c0r - d2r; t1i = c0i - d2i;
    t2r = d1r + d3r; t2i = d1i + d3i;
    t3r = d1r - d3r; t3i = d1i - d3i;
    xr[1] = t0r + t2r; xi[1] = t0i + t2i;
    xr[3] = t1r - t3i; xi[3] = t1i + t3r;
    xr[5] = t0r - t2r; xi[5] = t0i - t2i;
    xr[7] = t1r + t3i; xi[7] = t1i - t3r;
}

// multiply xr[1..7] by W^k1..W^{7k1} (conj if CONJ), w1 from 512-entry table
template <bool CONJ>
__device__ __forceinline__ void twmul7(float (&xr)[8], float (&xi)[8],
                                       const float* __restrict__ twr,
                                       const float* __restrict__ twi, int k1) {
    float w1r = twr[TPHYS(k1)];
    float w1i = CONJ ? -twi[TPHYS(k1)] : twi[TPHYS(k1)];
    float w2r, w2i, w3r, w3i, w4r, w4i, w5r, w5i, w6r, w6i, w7r, w7i;
    cmul(w1r, w1i, w1r, w1i, w2r, w2i);
    cmul(w2r, w2i, w1r, w1i, w3r, w3i);
    cmul(w2r, w2i, w2r, w2i, w4r, w4i);
    cmul(w4r, w4i, w1r, w1i, w5r, w5i);
    cmul(w4r, w4i, w2r, w2i, w6r, w6i);
    cmul(w4r, w4i, w3r, w3i, w7r, w7i);
    float orr, oii;
    cmul(xr[1], xi[1], w1r, w1i, orr, oii); xr[1] = orr; xi[1] = oii;
    cmul(xr[2], xi[2], w2r, w2i, orr, oii); xr[2] = orr; xi[2] = oii;
    cmul(xr[3], xi[3], w3r, w3i, orr, oii); xr[3] = orr; xi[3] = oii;
    cmul(xr[4], xi[4], w4r, w4i, orr, oii); xr[4] = orr; xi[4] = oii;
    cmul(xr[5], xi[5], w5r, w5i, orr, oii); xr[5] = orr; xi[5] = oii;
    cmul(xr[6], xi[6], w6r, w6i, orr, oii); xr[6] = orr; xi[6] = oii;
    cmul(xr[7], xi[7], w7r, w7i, orr, oii); xr[7] = orr; xi[7] = oii;
}

// Forward DIF stages 0..2 (LDS); stage 3 is done in registers by the caller.
__device__ void dif_head(float* __restrict__ ar, float* __restrict__ ai,
                         const float* __restrict__ twr, const float* __restrict__ twi,
                         int tid) {
#pragma unroll
    for (int s = 0; s < 3; ++s) {
        __syncthreads();
        const int eshift = 3 * (3 - s);
        const int E = 1 << eshift;
        int j = tid & (E - 1);
        int g = tid >> eshift;
        int base = (g << (eshift + 3)) + j;
        float xr[8], xi[8];
#pragma unroll
        for (int m = 0; m < 8; ++m) {
            int idx = APHYS(base + (m << eshift));
            xr[m] = ar[idx]; xi[m] = ai[idx];
        }
        dft8_fwd(xr, xi);
        twmul7<false>(xr, xi, twr, twi, j << (3 * s));
#pragma unroll
        for (int m = 0; m < 8; ++m) {
            int idx = APHYS(base + (m << eshift));
            ar[idx] = xr[m]; ai[idx] = xi[m];
        }
    }
}

// Inverse DIT stages 1..3 (LDS); stage 0 was done in registers by the caller.
__device__ void dit_tail(float* __restrict__ ar, float* __restrict__ ai,
                         const float* __restrict__ twr, const float* __restrict__ twi,
                         int tid) {
#pragma unroll
    for (int s = 1; s < 4; ++s) {
        __syncthreads();
        const int eshift = 3 * s;
        const int E = 1 << eshift;
        int j = tid & (E - 1);
        int g = tid >> eshift;
        int base = (g << (eshift + 3)) + j;
        float xr[8], xi[8];
#pragma unroll
        for (int m = 0; m < 8; ++m) {
            int idx = APHYS(base + (m << eshift));
            xr[m] = ar[idx]; xi[m] = ai[idx];
        }
        twmul7<true>(xr, xi, twr, twi, j << (3 * (3 - s)));
        dft8_inv(xr, xi);
#pragma unroll
        for (int m = 0; m < 8; ++m) {
            int idx = APHYS(base + (m << eshift));
            ar[idx] = xr[m]; ai[idx] = xi[m];
        }
    }
}

// One WG (512 thr) per (batch, channel-pair). Fwd stage3 + spectrum kept in
// registers (ownership 8*tid+m); band mask is a compile-time table over m
// (f = 512m + drev3(tid)); inverse stage0 fused on registers. Saves the mask
// pass, the spectrum readback, and 2 barriers/FFT vs r10. Conv/store as r10.
__global__ __launch_bounds__(512) void k_bands(
    const float* __restrict__ x,
    const float* __restrict__ cw0, const float* __restrict__ cw1,
    const float* __restrict__ cw2, const float* __restrict__ cw3,
    const float* __restrict__ bng, const float* __restrict__ bnb,
    const float* __restrict__ bnm, const float* __restrict__ bnv,
    const float* __restrict__ sw, const float* __restrict__ alp,
    unsigned int* __restrict__ Fu) {
    __shared__ float zr[LEN + 16], zi[LEN + 16];   // halo +-8
    __shared__ float wr[4224], wi[4224];           // APHYS(4095)=4222
    __shared__ float twr[528], twi[528];           // TPHYS(511)=526

    const int tid = threadIdx.x;
    const int pair = blockIdx.x;   // 0..63
    const int b = blockIdx.y;
    const int c0 = 2 * pair, c1 = c0 + 1;

    const float* xp0 = x + ((size_t)b * 128 + c0) * LEN;
    const float* xp1 = xp0 + LEN;
#pragma unroll
    for (int p = 0; p < PELEM; ++p) {
        int l = tid + NTHREADS * p;
        float a0 = xp0[l], a1 = xp1[l];
        zr[ZOFF + l] = a0; zi[ZOFF + l] = a1;
        wr[APHYS(l)] = a0; wi[APHYS(l)] = a1;
    }
    if (tid < 8) {
        zr[tid] = 0.f; zi[tid] = 0.f;
        zr[ZOFF + LEN + tid] = 0.f; zi[ZOFF + LEN + tid] = 0.f;
    }
    {
        int jj = tid;   // 512 entries, one per thread
        float ang = -(float)(2.0 * M_PI / 4096.0) * (float)jj;
        float sv, cv;
        sincosf(ang, &sv, &cv);
        twr[TPHYS(jj)] = cv; twi[TPHYS(jj)] = sv;
    }

    dif_head(wr, wi, twr, twi, tid);   // stages 0..2 (stage-top syncs)
    // forward stage 3: thread-local contiguous 8*tid+m, no twiddle, keep regs
    float Zr[8], Zi[8];
    __syncthreads();
#pragma unroll
    for (int m = 0; m < 8; ++m) {
        int idx = APHYS(8 * tid + m);
        Zr[m] = wr[idx]; Zi[m] = wi[idx];
    }
    dft8_fwd(Zr, Zi);

    // band of element m: f = 512*m + D, D = drev3(tid); fold + >>9 gives BM;
    // D==0 (tid 0 only) folds onto band edges -> BM0 fixup.
    const int D = drev3(tid);
    const int BM[8]  = {0, 1, 2, 3, 3, 2, 1, 0};
    const int BM0[8] = {0, 1, 2, 3, 3, 3, 2, 1};

    float s0w = sw[0], s1w = sw[1], s2w = sw[2], s3w = sw[3];
    float mx = fmaxf(fmaxf(s0w, s1w), fmaxf(s2w, s3w));
    float e0 = expf(s0w - mx), e1 = expf(s1w - mx), e2 = expf(s2w - mx), e3 = expf(s3w - mx);
    float esum = e0 + e1 + e2 + e3;
    float nwv[4] = {e0 / esum, e1 / esum, e2 / esum, e3 / esum};
    float alpha_s = 1.0f / (1.0f + expf(-alp[0]));
    float oma = 1.0f - alpha_s;

    const float* cwp[4] = {cw0, cw1, cw2, cw3};
    const int kk4[4] = {3, 5, 7, 11};

    float accr[PELEM], acci[PELEM];
#pragma unroll
    for (int p = 0; p < PELEM; ++p) { accr[p] = 0.f; acci[p] = 0.f; }

    unsigned int* dst = Fu + (size_t)b * (512 * LEN / 2);
    const int n = tid & 15;

#pragma unroll
    for (int band = 0; band < 4; ++band) {
        if (band < 3) {
            // fused mask + inverse stage 0 on registers
            float xr[8], xi[8];
#pragma unroll
            for (int m = 0; m < 8; ++m) {
                int bb = (D != 0) ? BM[m] : BM0[m];
                bool keep = (bb == band);
                xr[m] = keep ? Zr[m] : 0.0f;
                xi[m] = keep ? Zi[m] : 0.0f;
            }
            dft8_inv(xr, xi);
            __syncthreads();   // prev readers of wr (fwd s3 / prev conv) done
#pragma unroll
            for (int m = 0; m < 8; ++m) {
                int idx = APHYS(8 * tid + m);
                wr[idx] = xr[m]; wi[idx] = xi[m];
            }
            dit_tail(wr, wi, twr, twi, tid);   // stages 1..3 (stage-top syncs)
        }

        const float* cw = cwp[band];
        const int kk = kk4[band];
        const int kh = kk >> 1;
        float w0c[11], w1c[11];
        for (int q = 0; q < kk; ++q) {
            w0c[q] = cw[c0 * kk + q];
            w1c[q] = cw[c1 * kk + q];
        }
        float A0 = rsqrtf(bnv[band * 128 + c0] + 1e-5f) * bng[band * 128 + c0];
        float B0 = bnb[band * 128 + c0] - bnm[band * 128 + c0] * A0;
        float A1 = rsqrtf(bnv[band * 128 + c1] + 1e-5f) * bng[band * 128 + c1];
        float B1 = bnb[band * 128 + c1] - bnm[band * 128 + c1] * A1;
        float nww = nwv[band];
#pragma unroll
        for (int p = 0; p < PELEM; ++p) {
            int l = tid + NTHREADS * p;
            float bvr, bvi;
            if (band < 3) {
                bvr = wr[APHYS(l)] * INVN;   // own l-slot (stage3 wrote it)
                bvi = wi[APHYS(l)] * INVN;
                accr[p] += bvr;
                acci[p] += bvi;
            } else {
                bvr = zr[ZOFF + l] - accr[p];
                bvi = zi[ZOFF + l] - acci[p];
            }
            float s0 = 0.f, s1 = 0.f;
#pragma unroll
            for (int q = 0; q < 11; ++q) {
                if (q < kk) {
                    int idx = ZOFF + l + q - kh;   // halo: always in-bounds
                    s0 += zr[idx] * w0c[q];
                    s1 += zi[idx] * w1c[q];
                }
            }
            float y0 = s0 * A0 + B0;
            y0 = 0.5f * y0 * (1.0f + erff(y0 * RHALF)) * nww;
            float y1 = s1 * A1 + B1;
            y1 = 0.5f * y1 * (1.0f + erff(y1 * RHALF)) * nww;
            float f0 = alpha_s * y0 + oma * bvr;
            float f1 = alpha_s * y1 + oma * bvi;
            int lb = (tid >> 4) + 32 * p;   // l>>4 with l = tid + 512p
            unsigned int val = (unsigned int)f2bf(f0) | ((unsigned int)f2bf(f1) << 16);
            // k-permutation: g = pair, j = 2*band + (c&1) -> u32 slot = band
            dst[((lb * 64 + pair) * 16 + n) * 4 + band] = val;
        }
    }
}

// W (fp32 [256][512]) -> bf16 in MFMA A-fragment order, matching k-permutation:
// k = band*128 + 2*pair + lo  ->  (g = pair, j = 2*band + lo)
__global__ void k_prep(const float* __restrict__ pw, unsigned short* __restrict__ Wq) {
    int idx = blockIdx.x * 256 + threadIdx.x;   // 131072
    int o = idx >> 9, c = idx & 511;
    int band = c >> 7, pair = (c & 127) >> 1, lo = c & 1;
    int dstidx = (((o >> 4) * 64 + pair) * 16 + (o & 15)) * 8 + 2 * band + lo;
    Wq[dstidx] = f2bf(pw[idx]);
}

// LDS-free MFMA GEMM: out[b,o,l] = bias[o] + sum_k W[o,k]*F[b,k,l]
__global__ __launch_bounds__(256) void k_gemm(
    const unsigned short* __restrict__ Wq, const unsigned short* __restrict__ Fq,
    const float* __restrict__ pb, float* __restrict__ out) {
    const int tid = threadIdx.x;
    const int wave = tid >> 6, lane = tid & 63;
    const int h = lane >> 4, n16 = lane & 15;
    const int lt = blockIdx.x, b = blockIdx.y;
    const unsigned short* Fb = Fq + (size_t)b * 2097152;

    f32x4 acc[4][4];
#pragma unroll
    for (int mi = 0; mi < 4; ++mi)
#pragma unroll
        for (int ni = 0; ni < 4; ++ni) acc[mi][ni] = (f32x4){0.f, 0.f, 0.f, 0.f};

#pragma unroll
    for (int ks = 0; ks < 16; ++ks) {
        bf16x8 af[4], bfr[4];
#pragma unroll
        for (int mi = 0; mi < 4; ++mi) {
            int mb = wave * 4 + mi;
            af[mi] = *(const bf16x8*)(Wq + ((((mb * 64) + 4 * ks + h) * 16 + n16) << 3));
        }
#pragma unroll
        for (int ni = 0; ni < 4; ++ni) {
            int lb = lt * 4 + ni;
            bfr[ni] = *(const bf16x8*)(Fb + ((((lb * 64) + 4 * ks + h) * 16 + n16) << 3));
        }
#pragma unroll
        for (int mi = 0; mi < 4; ++mi)
#pragma unroll
            for (int ni = 0; ni < 4; ++ni)
                acc[mi][ni] = __builtin_amdgcn_mfma_f32_16x16x32_bf16(
                    af[mi], bfr[ni], acc[mi][ni], 0, 0, 0);
    }

#pragma unroll
    for (int mi = 0; mi < 4; ++mi) {
#pragma unroll
        for (int r = 0; r < 4; ++r) {
            int o = wave * 64 + mi * 16 + h * 4 + r;
            float bias = pb[o];
#pragma unroll
            for (int ni = 0; ni < 4; ++ni) {
                int l = lt * 64 + ni * 16 + n16;
                out[((size_t)(b * 256 + o)) * LEN + l] = acc[mi][ni][r] + bias;
            }
        }
    }
}

extern "C" void kernel_launch(void* const* d_in, const int* in_sizes, int n_in,
                              void* d_out, int out_size, void* d_ws, size_t ws_size,
                              hipStream_t stream) {
    const float* x   = (const float*)d_in[0];
    const float* cw0 = (const float*)d_in[1];
    const float* cw1 = (const float*)d_in[2];
    const float* cw2 = (const float*)d_in[3];
    const float* cw3 = (const float*)d_in[4];
    const float* bng = (const float*)d_in[5];
    const float* bnb = (const float*)d_in[6];
    const float* bnm = (const float*)d_in[7];
    const float* bnv = (const float*)d_in[8];
    const float* sw  = (const float*)d_in[9];
    const float* alp = (const float*)d_in[10];
    const float* pw  = (const float*)d_in[11];
    const float* pb  = (const float*)d_in[12];
    float* out = (float*)d_out;

    unsigned short* Wq = (unsigned short*)d_ws;                       // 256 KB
    unsigned int* Fu = (unsigned int*)((char*)d_ws + 262144);         // 4 MB/batch

    k_prep<<<512, 256, 0, stream>>>(pw, Wq);

    const size_t perB = (size_t)512 * LEN * 2;   // 4 MiB bf16 per batch
    int chunk = (int)((ws_size > 262144 ? ws_size - 262144 : 0) / perB);
    if (chunk < 1) chunk = 1;
    if (chunk > 16) chunk = 16;

    for (int b0 = 0; b0 < 16; b0 += chunk) {
        int nb = 16 - b0 < chunk ? 16 - b0 : chunk;
        dim3 g1(64, nb);
        k_bands<<<g1, NTHREADS, 0, stream>>>(
            x + (size_t)b0 * 128 * LEN, cw0, cw1, cw2, cw3,
            bng, bnb, bnm, bnv, sw, alp, Fu);
        dim3 g2(64, nb);
        k_gemm<<<g2, 256, 0, stream>>>(
            Wq, (const unsigned short*)Fu, pb, out + (size_t)b0 * 256 * LEN);
    }
}